// Round 10
// baseline (3183.671 us; speedup 1.0000x reference)
//
#include <hip/hip_runtime.h>
#include <math.h>

#define T_STEPS 50
#define NT 768

// workspace layout (float offsets)
#define WS_FC1T 0          // 1600*256 = 409600 : fc1_w transposed [k][j]
#define WS_W2F  409600     // 32*9*64*4 = 73728 : folded conv2, tap-quad-major [ic][q][oc][4]
#define WS_W1F  483328     // 36*64 = 2304 : folded conv1 [j][oc*2+ic]
#define WS_WOUTP 485632    // 2816 : fc_out packed [(o*64+lane)*4+k] = fc_out[o*256+k*64+lane]
#define WS_TOTAL 488448

// LDS layout (float offsets). 40240 floats = 160960 B <= 163840 (160 KiB).
// IPART2 aliases RED[0..3072): RED written phase 3 (B..C), read phase 4 (..D);
// IPART2 written phase 5 (D..E), read by wave 0 at the TOP of the next step
// (before barrier B, i.e. before the next RED write). Safe by barrier ordering.
#define L_XT    0          // 2080 : x_t tile, ic-stride 1040 (bank-conflict fix)
#define L_SPK1  2080       // 7296 : 32 planes, stride 228
#define L_RED   9376       // 19200 : 12 conv2 partial buffers
#define L_IPART2 L_RED     // 3072 alias : fc1 partials, 12 waves x 256
#define L_LIST  28576      // 1600 (ints)
#define L_FLAG  30176      // 448
#define L_CNT   30624      // 16
#define L_VC1   30640      // 6272 : conv1 membrane, [py*14+px]*32 + oc
#define L_VC2   36912      // 1600
#define L_BN2   38512      // 192 : s2 | sh2 | b2
#define L_FCP   38704      // 768 : alpha | rho | beta_a
#define L_FCS   39472      // 768 : vfc | afc | spf
#define L_TOTALF 40240
#define SMEM_BYTES (L_TOTALF * 4)

__global__ void prep_kernel(const float* __restrict__ conv1_w,
                            const float* __restrict__ conv2_w,
                            const float* __restrict__ fc1_w,
                            const float* __restrict__ fc_out_w,
                            float* __restrict__ ws) {
  int i = blockIdx.x * blockDim.x + threadIdx.x;
  if (i < 409600) {
    int k = i >> 8, j = i & 255;
    ws[WS_FC1T + i] = fc1_w[j * 1600 + k];
  } else if (i < 483328) {
    // tap-quad-major: i2 = ((ic*9 + q)*64 + oc)*4 + r, tap jj = 4q + r
    int i2 = i - 409600;
    int r  = i2 & 3;
    int t2 = i2 >> 2;
    int oc = t2 & 63;
    int t3 = t2 >> 6;      // ic*9 + q
    int q  = t3 % 9;
    int ic = t3 / 9;
    int jj = q * 4 + r, u = jj / 6, v = jj % 6;
    float s = 0.f;
    for (int dy = 0; dy < 2; ++dy) {
      int ky = u - dy; if (ky < 0 || ky > 4) continue;
      for (int dx = 0; dx < 2; ++dx) {
        int kx = v - dx; if (kx < 0 || kx > 4) continue;
        s += conv2_w[((oc * 32 + ic) * 5 + ky) * 5 + kx];
      }
    }
    ws[WS_W2F + i2] = 0.25f * s;
  } else if (i < 485632) {
    int i3 = i - 483328;
    int jj = i3 >> 6, l = i3 & 63, oc = l >> 1, ic = l & 1, u = jj / 6, v = jj % 6;
    float s = 0.f;
    for (int dy = 0; dy < 2; ++dy) {
      int ky = u - dy; if (ky < 0 || ky > 4) continue;
      for (int dx = 0; dx < 2; ++dx) {
        int kx = v - dx; if (kx < 0 || kx > 4) continue;
        s += conv1_w[((oc * 2 + ic) * 5 + ky) * 5 + kx];
      }
    }
    ws[WS_W1F + i3] = 0.25f * s;
  } else if (i < WS_TOTAL) {
    // fc_out packed for per-lane float4 loads in phase 6
    int i4 = i - 485632;
    int k  = i4 & 3;
    int s_ = i4 >> 2;
    int ln = s_ & 63;
    int o  = s_ >> 6;
    ws[WS_WOUTP + i4] = fc_out_w[o * 256 + k * 64 + ln];
  }
}

// conv2 weight load: 9 coalesced 1KB wave-loads into a named register array.
// Macro (not lambda) so the destination array is always statically indexed.
#define LOADW(WD, IC) {                                                      \
    const float4* wp_ = ((const float4*)w2f) + ((IC) * 9) * 64 + lane;       \
    _Pragma("unroll")                                                        \
    for (int q_ = 0; q_ < 9; ++q_) {                                         \
      float4 f_ = wp_[q_ * 64];                                              \
      WD[4*q_] = f_.x; WD[4*q_+1] = f_.y; WD[4*q_+2] = f_.z; WD[4*q_+3] = f_.w; \
    } }

// conv2 compute for one ic with weights WD and 14-bit row-liveness mask MM.
#define COMPW(WD, IC, MM) {                                                  \
    const float* srow_ = &sm[L_SPK1 + (IC) * 228];                           \
    _Pragma("unroll")                                                        \
    for (int iy_ = 0; iy_ < 14; ++iy_) {                                     \
      if ((MM) & (1u << iy_)) {                                              \
        float row_[16];                                                      \
        const float4* rp_ = (const float4*)&srow_[iy_ * 16];                 \
        _Pragma("unroll")                                                    \
        for (int q_ = 0; q_ < 4; ++q_) {                                     \
          float4 f_ = rp_[q_];                                               \
          row_[4*q_] = f_.x; row_[4*q_+1] = f_.y; row_[4*q_+2] = f_.z; row_[4*q_+3] = f_.w; \
        }                                                                    \
        _Pragma("unroll")                                                    \
        for (int py_ = 0; py_ < 5; ++py_) {                                  \
          const int u_ = iy_ - 2 * py_;                                      \
          if (u_ >= 0 && u_ <= 5) {                                          \
            _Pragma("unroll")                                                \
            for (int v_ = 0; v_ < 6; ++v_) {                                 \
              float wv_ = WD[u_ * 6 + v_];                                   \
              _Pragma("unroll")                                              \
              for (int px_ = 0; px_ < 5; ++px_)                              \
                acc[py_ * 5 + px_] += row_[2*px_ + v_] * wv_;                \
            }                                                                \
          }                                                                  \
        }                                                                    \
      }                                                                      \
    } }

// block = 768 (12 waves), LDS 160.9KB -> 1 WG/CU = 3 waves/SIMD.
// VGPR: __launch_bounds__(768, 1). Empirical allocator law fitted on 5 configs:
// arg2 acts as WORKGROUPS-PER-CU -> granted VGPR = 512/(arg2 * 12waves / 4simd).
// arg2=2 granted 84 (the straitjacket that made R8's ping-pong spill 5 GB);
// arg2=1 -> 12 waves/CU = 3/SIMD -> ~170 VGPR, exactly the HW limit for our
// real (LDS-bound, 1 WG) occupancy. 3x170=510<=512, so residency unchanged.
// Pipeline (5 barriers/step):
//   step top : wave 0 runs PHASE 6 of t-1; waves 1-7 conv1(t) in ROW PAIRS
//              (8 shared input rows read once per pair: 448 vs 672 LDS reads)
//   barrier B: conv2 on all 12 waves with PING-PONG WEIGHT PREFETCH --
//              flags hoisted to bitmasks first, then ic(k+1)'s 9 weight loads
//              are issued before ic(k)'s compute (hides ~300cy L2 latency).
//   barrier C: phase 4 reduce/LIF/list
//   barrier D: phase 5 fc1 gather + XT(t+1) commit
//   barrier E: next step
__global__ __launch_bounds__(NT, 1) void snn_kernel(
    const float* __restrict__ x,
    const float* __restrict__ bn1_gamma, const float* __restrict__ bn1_beta,
    const float* __restrict__ bn1_mean,  const float* __restrict__ bn1_var,
    const float* __restrict__ bn2_gamma, const float* __restrict__ bn2_beta,
    const float* __restrict__ bn2_mean,  const float* __restrict__ bn2_var,
    const float* __restrict__ beta_c1_raw, const float* __restrict__ beta_c2_raw,
    const float* __restrict__ alpha_raw, const float* __restrict__ rho_raw,
    const float* __restrict__ beta_a_p,  const float* __restrict__ fc_out_w,
    const float* __restrict__ beta_out_p,
    const float* __restrict__ ws, float* __restrict__ out)
{
  extern __shared__ float sm[];
  int* listI = (int*)&sm[L_LIST];
  int* cntI  = (int*)&sm[L_CNT];
  const int tid = threadIdx.x, wave = tid >> 6, lane = tid & 63;
  const int b = blockIdx.x;

  // one-time state zero-init + param staging
  for (int i = tid; i < 6272; i += NT) sm[L_VC1 + i] = 0.f;
  for (int i = tid; i < 1600; i += NT) sm[L_VC2 + i] = 0.f;
  if (tid < 256) {
    sm[L_FCP + tid]       = 1.f / (1.f + expf(-alpha_raw[tid]));
    sm[L_FCP + 256 + tid] = 1.f / (1.f + expf(-rho_raw[tid]));
    sm[L_FCP + 512 + tid] = beta_a_p[tid];
    sm[L_FCS + tid] = 0.f;
    sm[L_FCS + 256 + tid] = 0.f;
    sm[L_FCS + 512 + tid] = 0.f;
  }
  if (tid < 64) {
    float s2 = bn2_gamma[tid] / sqrtf(bn2_var[tid] + 1e-5f);
    sm[L_BN2 + tid]       = s2;
    sm[L_BN2 + 64 + tid]  = bn2_beta[tid] - bn2_mean[tid] * s2;
    sm[L_BN2 + 128 + tid] = 1.f / (1.f + expf(-beta_c2_raw[tid]));
  }

  // conv1 lane mapping: lane = oc*2 + ic
  const int oc1 = lane >> 1, ic1 = lane & 1;
  const float s1v  = bn1_gamma[oc1] / sqrtf(bn1_var[oc1] + 1e-5f);
  const float sh1v = bn1_beta[oc1] - bn1_mean[oc1] * s1v;
  const float b1v  = 1.f / (1.f + expf(-beta_c1_raw[oc1]));
  const float beta_o = 1.f / (1.f + expf(-beta_out_p[0]));

  // conv1 weights: persistent in registers (36 regs)
  float w1r[36];
  #pragma unroll
  for (int j = 0; j < 36; ++j) w1r[j] = ws[WS_W1F + j * 64 + lane];

  float v_out = 0.f, o_sum = 0.f;  // wave0, lane<11

  const float* xbase = x + (size_t)b * T_STEPS * 2048;
  const float* w2f  = ws + WS_W2F;
  const float* fc1T = ws + WS_FC1T;

  // prologue: load+commit x0, prefetch x1
  float4 xpre;
  if (tid < 512) {
    float4 x0 = ((const float4*)xbase)[tid];
    *(float4*)&sm[L_XT + (tid >> 8) * 1040 + ((tid & 255) << 2)] = x0;
    int tn = (T_STEPS > 1) ? 1 : 0;
    xpre = ((const float4*)(xbase + tn * 2048))[tid];
  }

  __syncthreads();

  for (int t = 0; t < T_STEPS; ++t) {
    // ---- phase 2 region: wave 0 phase6(t-1); waves 1-7 conv1(t) row pairs ----
    if (wave == 0) {
      if (t > 0) {
        float sk[4];
        #pragma unroll
        for (int k = 0; k < 4; ++k) {
          int j = lane + 64 * k;
          float I = 0.f;
          #pragma unroll
          for (int h2 = 0; h2 < 12; ++h2) I += sm[L_IPART2 + h2 * 256 + j];
          float al = sm[L_FCP + j], rh = sm[L_FCP + 256 + j], ba = sm[L_FCP + 512 + j];
          float vf = sm[L_FCS + j], af = sm[L_FCS + 256 + j], sp0 = sm[L_FCS + 512 + j];
          af = rh * af + (1.f - rh) * sp0;
          float v = al * vf + (1.f - al) * I;
          float sp = (v > 1.f + ba * af) ? 1.f : 0.f;
          sm[L_FCS + j] = v * (1.f - sp);
          sm[L_FCS + 256 + j] = af;
          sm[L_FCS + 512 + j] = sp;
          sk[k] = sp;
        }
        const float4* wop = ((const float4*)(ws + WS_WOUTP)) + lane;
        float p[11];
        #pragma unroll
        for (int o = 0; o < 11; ++o) {
          float4 f = wop[o * 64];          // coalesced, L2-hot
          p[o] = sk[0] * f.x + sk[1] * f.y + sk[2] * f.z + sk[3] * f.w;
        }
        #pragma unroll
        for (int m = 1; m < 64; m <<= 1)
          #pragma unroll
          for (int o = 0; o < 11; ++o) p[o] += __shfl_xor(p[o], m);
        float Isel = p[0];
        #pragma unroll
        for (int o = 1; o < 11; ++o) Isel = (lane == o) ? p[o] : Isel;
        if (lane < 11) {
          v_out = beta_o * v_out + (1.f - beta_o) * Isel;
          o_sum += v_out;
        }
      }
      if (lane == 0) *cntI = 0;
    } else if (wave <= 7) {
      // conv1 row pair py0 = 2*(wave-1), py1 = py0+1.
      // Input rows 2*py0 .. 2*py0+7 read ONCE and used for both outputs.
      const int py0 = (wave - 1) * 2;
      const int py1 = py0 + 1;
      float acc0[14], acc1[14];
      #pragma unroll
      for (int p = 0; p < 14; ++p) { acc0[p] = 0.f; acc1[p] = 0.f; }
      const float* xr = &sm[L_XT + ic1 * 1040 + py0 * 64];
      #pragma unroll
      for (int rr = 0; rr < 8; ++rr) {
        float row[32];
        const float4* rp = (const float4*)&xr[rr * 32];
        #pragma unroll
        for (int q = 0; q < 8; ++q) {
          float4 f = rp[q];
          row[4*q] = f.x; row[4*q+1] = f.y; row[4*q+2] = f.z; row[4*q+3] = f.w;
        }
        if (rr <= 5) {                 // tap u = rr for py0
          #pragma unroll
          for (int v = 0; v < 6; ++v) {
            float wv = w1r[rr * 6 + v];
            #pragma unroll
            for (int px = 0; px < 14; ++px) acc0[px] += row[2*px + v] * wv;
          }
        }
        if (rr >= 2) {                 // tap u = rr-2 for py1
          #pragma unroll
          for (int v = 0; v < 6; ++v) {
            float wv = w1r[(rr - 2) * 6 + v];
            #pragma unroll
            for (int px = 0; px < 14; ++px) acc1[px] += row[2*px + v] * wv;
          }
        }
      }
      #pragma unroll
      for (int px = 0; px < 14; ++px) {
        acc0[px] += __shfl_xor(acc0[px], 1);
        acc1[px] += __shfl_xor(acc1[px], 1);
      }
      if (ic1 == 0) {
        float flag0 = 0.f, flag1 = 0.f;
        #pragma unroll
        for (int px = 0; px < 14; ++px) {
          float c0 = acc0[px] * s1v + sh1v;
          float c1 = acc1[px] * s1v + sh1v;
          const int vi0 = L_VC1 + (py0 * 14 + px) * 32 + oc1;
          const int vi1 = L_VC1 + (py1 * 14 + px) * 32 + oc1;
          float v0 = b1v * sm[vi0] + (1.f - b1v) * c0;
          float v1 = b1v * sm[vi1] + (1.f - b1v) * c1;
          float s0 = (v0 > 1.f) ? 1.f : 0.f;
          float s1 = (v1 > 1.f) ? 1.f : 0.f;
          sm[vi0] = v0 * (1.f - s0);
          sm[vi1] = v1 * (1.f - s1);
          sm[L_SPK1 + oc1 * 228 + py0 * 16 + px] = s0;
          sm[L_SPK1 + oc1 * 228 + py1 * 16 + px] = s1;
          flag0 += s0; flag1 += s1;
        }
        sm[L_FLAG + oc1 * 14 + py0] = flag0;
        sm[L_FLAG + oc1 * 14 + py1] = flag1;
      }
    }
    __syncthreads();                                     // barrier B

    // ---- phase 3: conv2, 12 waves, ping-pong weight prefetch ----
    {
      const bool three = (wave < 8);
      const int ic0_ = three ? wave : (16 + wave);
      const int icst = three ? 8 : 4;
      const int ic1_ = ic0_ + icst;
      const int ic2_ = ic0_ + 2 * icst;   // only used when three

      // hoist flag reads -> 14-bit masks (breaks flag->load dependency)
      unsigned m0 = 0, m1 = 0, m2 = 0;
      {
        const float* f0 = &sm[L_FLAG + ic0_ * 14];
        const float* f1 = &sm[L_FLAG + ic1_ * 14];
        #pragma unroll
        for (int iy = 0; iy < 14; ++iy) {
          m0 |= (f0[iy] != 0.f) ? (1u << iy) : 0u;
          m1 |= (f1[iy] != 0.f) ? (1u << iy) : 0u;
        }
        if (three) {
          const float* f2 = &sm[L_FLAG + ic2_ * 14];
          #pragma unroll
          for (int iy = 0; iy < 14; ++iy)
            m2 |= (f2[iy] != 0.f) ? (1u << iy) : 0u;
        }
      }

      float acc[25];
      #pragma unroll
      for (int p = 0; p < 25; ++p) acc[p] = 0.f;

      float wA[36], wB[36];
      // ping-pong: next ic's loads are in flight while current ic computes.
      if (m0) LOADW(wA, ic0_)
      if (m1) LOADW(wB, ic1_)
      if (m0) COMPW(wA, ic0_, m0)
      if (three && m2) LOADW(wA, ic2_)     // wA dead after its compute (or unused)
      if (m1) COMPW(wB, ic1_, m1)
      if (three && m2) COMPW(wA, ic2_, m2)

      #pragma unroll
      for (int p = 0; p < 25; ++p) sm[L_RED + wave * 1600 + lane * 25 + p] = acc[p];
    }
    __syncthreads();                                     // barrier C

    // ---- phase 4: reduce 12 buffers + BN + LIF -> spike list ----
    {
      #pragma unroll
      for (int k = 0; k < 3; ++k) {
        int n = tid + NT * k;
        float s = 0.f;
        if (n < 1600) {
          float ssum = 0.f;
          #pragma unroll
          for (int wv = 0; wv < 12; ++wv) ssum += sm[L_RED + wv * 1600 + n];
          int oc = n / 25;
          float c2 = ssum * sm[L_BN2 + oc] + sm[L_BN2 + 64 + oc];
          float b2 = sm[L_BN2 + 128 + oc];
          const int vidx = L_VC2 + n;
          float vold = sm[vidx];
          float v = b2 * vold + (1.f - b2) * c2;
          s = (v > 1.f) ? 1.f : 0.f;
          sm[vidx] = v * (1.f - s);
        }
        unsigned long long mask = __ballot(s > 0.f);
        if (mask) {
          int base = 0;
          if (lane == 0) base = atomicAdd(cntI, __popcll(mask));
          base = __shfl(base, 0);
          if (s > 0.f) {
            int pos = __popcll(mask & ((1ull << lane) - 1ull));
            listI[base + pos] = n;
          }
        }
      }
    }
    __syncthreads();                                     // barrier D

    // ---- phase 5: fc1 sparse gather (12-way, 4 accs) + XT(t+1) commit ----
    {
      if (tid < 512) {
        *(float4*)&sm[L_XT + (tid >> 8) * 1040 + ((tid & 255) << 2)] = xpre;
        int tn = (t + 2 < T_STEPS) ? t + 2 : T_STEPS - 1;
        xpre = ((const float4*)(xbase + tn * 2048))[tid];
      }
      const int nn = *cntI;
      const float4* fc4 = (const float4*)fc1T;
      float4 a0 = {0.f,0.f,0.f,0.f}, a1 = {0.f,0.f,0.f,0.f};
      float4 a2 = {0.f,0.f,0.f,0.f}, a3 = {0.f,0.f,0.f,0.f};
      int i = wave;
      for (; i + 36 < nn; i += 48) {
        int k0 = listI[i], k1 = listI[i + 12], k2 = listI[i + 24], k3 = listI[i + 36];
        float4 f0 = fc4[k0 * 64 + lane];
        float4 f1 = fc4[k1 * 64 + lane];
        float4 f2 = fc4[k2 * 64 + lane];
        float4 f3 = fc4[k3 * 64 + lane];
        a0.x += f0.x; a0.y += f0.y; a0.z += f0.z; a0.w += f0.w;
        a1.x += f1.x; a1.y += f1.y; a1.z += f1.z; a1.w += f1.w;
        a2.x += f2.x; a2.y += f2.y; a2.z += f2.z; a2.w += f2.w;
        a3.x += f3.x; a3.y += f3.y; a3.z += f3.z; a3.w += f3.w;
      }
      for (; i < nn; i += 12) {
        int k = listI[i];
        float4 f = fc4[k * 64 + lane];
        a0.x += f.x; a0.y += f.y; a0.z += f.z; a0.w += f.w;
      }
      a0.x += a1.x + a2.x + a3.x;
      a0.y += a1.y + a2.y + a3.y;
      a0.z += a1.z + a2.z + a3.z;
      a0.w += a1.w + a2.w + a3.w;
      ((float4*)&sm[L_IPART2])[wave * 64 + lane] = a0;   // aliases RED[0..3072)
    }
    __syncthreads();                                     // barrier E
    // phase 6 for this t runs at the top of the next iteration (wave 0).
  }

  // epilogue: phase 6 for t = T_STEPS-1
  if (wave == 0) {
    float sk[4];
    #pragma unroll
    for (int k = 0; k < 4; ++k) {
      int j = lane + 64 * k;
      float I = 0.f;
      #pragma unroll
      for (int h2 = 0; h2 < 12; ++h2) I += sm[L_IPART2 + h2 * 256 + j];
      float al = sm[L_FCP + j], rh = sm[L_FCP + 256 + j], ba = sm[L_FCP + 512 + j];
      float vf = sm[L_FCS + j], af = sm[L_FCS + 256 + j], sp0 = sm[L_FCS + 512 + j];
      af = rh * af + (1.f - rh) * sp0;
      float v = al * vf + (1.f - al) * I;
      float sp = (v > 1.f + ba * af) ? 1.f : 0.f;
      sk[k] = sp;
    }
    const float4* wop = ((const float4*)(ws + WS_WOUTP)) + lane;
    float p[11];
    #pragma unroll
    for (int o = 0; o < 11; ++o) {
      float4 f = wop[o * 64];
      p[o] = sk[0] * f.x + sk[1] * f.y + sk[2] * f.z + sk[3] * f.w;
    }
    #pragma unroll
    for (int m = 1; m < 64; m <<= 1)
      #pragma unroll
      for (int o = 0; o < 11; ++o) p[o] += __shfl_xor(p[o], m);
    float Isel = p[0];
    #pragma unroll
    for (int o = 1; o < 11; ++o) Isel = (lane == o) ? p[o] : Isel;
    if (lane < 11) {
      v_out = beta_o * v_out + (1.f - beta_o) * Isel;
      o_sum += v_out;
      out[b * 11 + lane] = o_sum * (1.f / T_STEPS);
    }
  }
}

extern "C" void kernel_launch(void* const* d_in, const int* in_sizes, int n_in,
                              void* d_out, int out_size, void* d_ws, size_t ws_size,
                              hipStream_t stream) {
  const float* x            = (const float*)d_in[0];
  const float* conv1_w      = (const float*)d_in[1];
  const float* bn1_gamma    = (const float*)d_in[2];
  const float* bn1_beta     = (const float*)d_in[3];
  const float* bn1_mean     = (const float*)d_in[4];
  const float* bn1_var      = (const float*)d_in[5];
  const float* conv2_w      = (const float*)d_in[6];
  const float* bn2_gamma    = (const float*)d_in[7];
  const float* bn2_beta     = (const float*)d_in[8];
  const float* bn2_mean     = (const float*)d_in[9];
  const float* bn2_var      = (const float*)d_in[10];
  const float* beta_c1_raw  = (const float*)d_in[11];
  const float* beta_c2_raw  = (const float*)d_in[12];
  const float* fc1_w        = (const float*)d_in[13];
  const float* alpha_raw    = (const float*)d_in[14];
  const float* rho_raw      = (const float*)d_in[15];
  const float* beta_a_p     = (const float*)d_in[16];
  const float* fc_out_w     = (const float*)d_in[17];
  const float* beta_out_p   = (const float*)d_in[18];
  float* ws  = (float*)d_ws;
  float* outp = (float*)d_out;

  (void)in_sizes; (void)n_in; (void)out_size; (void)ws_size;

  hipFuncSetAttribute((const void*)snn_kernel,
                      hipFuncAttributeMaxDynamicSharedMemorySize, SMEM_BYTES);

  prep_kernel<<<dim3((WS_TOTAL + 255) / 256), dim3(256), 0, stream>>>(
      conv1_w, conv2_w, fc1_w, fc_out_w, ws);

  snn_kernel<<<dim3(128), dim3(NT), SMEM_BYTES, stream>>>(
      x, bn1_gamma, bn1_beta, bn1_mean, bn1_var,
      bn2_gamma, bn2_beta, bn2_mean, bn2_var,
      beta_c1_raw, beta_c2_raw, alpha_raw, rho_raw, beta_a_p,
      fc_out_w, beta_out_p, ws, outp);
}

// Round 11
// 1941.358 us; speedup vs baseline: 1.6399x; 1.6399x over previous
//
#include <hip/hip_runtime.h>
#include <math.h>

#define T_STEPS 50
#define NT 768

// workspace layout (float offsets)
#define WS_FC1T 0          // 1600*256 = 409600 : fc1_w transposed [k][j]
#define WS_W2F  409600     // 32*9*64*4 = 73728 : folded conv2, tap-quad-major [ic][q][oc][4]
#define WS_W1F  483328     // 36*64 = 2304 : folded conv1 [j][oc*2+ic]
#define WS_WOUTP 485632    // 2816 : fc_out packed [(o*64+lane)*4+k] = fc_out[o*256+k*64+lane]
#define WS_TOTAL 488448

// LDS layout (float offsets). 40240 floats = 160960 B <= 163840 (160 KiB).
// IPART2 aliases RED[0..3072): RED written phase 3 (B..C), read phase 4 (..D);
// IPART2 written phase 5 (D..E), read by wave 0 at the TOP of the next step
// (before barrier B, i.e. before the next RED write). Safe by barrier ordering.
#define L_XT    0          // 2080 : x_t tile, ic-stride 1040 (bank-conflict fix)
#define L_SPK1  2080       // 7296 : 32 planes, stride 228
#define L_RED   9376       // 19200 : 12 conv2 partial buffers
#define L_IPART2 L_RED     // 3072 alias : fc1 partials, 12 waves x 256
#define L_LIST  28576      // 1600 (ints)
#define L_FLAG  30176      // 448
#define L_CNT   30624      // 16
#define L_VC1   30640      // 6272 : conv1 membrane, [py*14+px]*32 + oc
#define L_VC2   36912      // 1600
#define L_BN2   38512      // 192 : s2 | sh2 | b2
#define L_FCP   38704      // 768 : alpha | rho | beta_a
#define L_FCS   39472      // 768 : vfc | afc | spf
#define L_TOTALF 40240
#define SMEM_BYTES (L_TOTALF * 4)

__global__ void prep_kernel(const float* __restrict__ conv1_w,
                            const float* __restrict__ conv2_w,
                            const float* __restrict__ fc1_w,
                            const float* __restrict__ fc_out_w,
                            float* __restrict__ ws) {
  int i = blockIdx.x * blockDim.x + threadIdx.x;
  if (i < 409600) {
    int k = i >> 8, j = i & 255;
    ws[WS_FC1T + i] = fc1_w[j * 1600 + k];
  } else if (i < 483328) {
    // tap-quad-major: i2 = ((ic*9 + q)*64 + oc)*4 + r, tap jj = 4q + r
    int i2 = i - 409600;
    int r  = i2 & 3;
    int t2 = i2 >> 2;
    int oc = t2 & 63;
    int t3 = t2 >> 6;      // ic*9 + q
    int q  = t3 % 9;
    int ic = t3 / 9;
    int jj = q * 4 + r, u = jj / 6, v = jj % 6;
    float s = 0.f;
    for (int dy = 0; dy < 2; ++dy) {
      int ky = u - dy; if (ky < 0 || ky > 4) continue;
      for (int dx = 0; dx < 2; ++dx) {
        int kx = v - dx; if (kx < 0 || kx > 4) continue;
        s += conv2_w[((oc * 32 + ic) * 5 + ky) * 5 + kx];
      }
    }
    ws[WS_W2F + i2] = 0.25f * s;
  } else if (i < 485632) {
    int i3 = i - 483328;
    int jj = i3 >> 6, l = i3 & 63, oc = l >> 1, ic = l & 1, u = jj / 6, v = jj % 6;
    float s = 0.f;
    for (int dy = 0; dy < 2; ++dy) {
      int ky = u - dy; if (ky < 0 || ky > 4) continue;
      for (int dx = 0; dx < 2; ++dx) {
        int kx = v - dx; if (kx < 0 || kx > 4) continue;
        s += conv1_w[((oc * 2 + ic) * 5 + ky) * 5 + kx];
      }
    }
    ws[WS_W1F + i3] = 0.25f * s;
  } else if (i < WS_TOTAL) {
    // fc_out packed for per-lane float4 loads in phase 6
    int i4 = i - 485632;
    int k  = i4 & 3;
    int s_ = i4 >> 2;
    int ln = s_ & 63;
    int o  = s_ >> 6;
    ws[WS_WOUTP + i4] = fc_out_w[o * 256 + k * 64 + ln];
  }
}

// conv2 weight load: 9 coalesced 1KB wave-loads into a named register array.
#define LOADW(WD, IC) {                                                      \
    const float4* wp_ = ((const float4*)w2f) + ((IC) * 9) * 64 + lane;       \
    _Pragma("unroll")                                                        \
    for (int q_ = 0; q_ < 9; ++q_) {                                         \
      float4 f_ = wp_[q_ * 64];                                              \
      WD[4*q_] = f_.x; WD[4*q_+1] = f_.y; WD[4*q_+2] = f_.z; WD[4*q_+3] = f_.w; \
    } }

// conv2 compute for one ic with weights WD and 14-bit row-liveness mask MM.
#define COMPW(WD, IC, MM) {                                                  \
    const float* srow_ = &sm[L_SPK1 + (IC) * 228];                           \
    _Pragma("unroll")                                                        \
    for (int iy_ = 0; iy_ < 14; ++iy_) {                                     \
      if ((MM) & (1u << iy_)) {                                              \
        float row_[16];                                                      \
        const float4* rp_ = (const float4*)&srow_[iy_ * 16];                 \
        _Pragma("unroll")                                                    \
        for (int q_ = 0; q_ < 4; ++q_) {                                     \
          float4 f_ = rp_[q_];                                               \
          row_[4*q_] = f_.x; row_[4*q_+1] = f_.y; row_[4*q_+2] = f_.z; row_[4*q_+3] = f_.w; \
        }                                                                    \
        _Pragma("unroll")                                                    \
        for (int py_ = 0; py_ < 5; ++py_) {                                  \
          const int u_ = iy_ - 2 * py_;                                      \
          if (u_ >= 0 && u_ <= 5) {                                          \
            _Pragma("unroll")                                                \
            for (int v_ = 0; v_ < 6; ++v_) {                                 \
              float wv_ = WD[u_ * 6 + v_];                                   \
              _Pragma("unroll")                                              \
              for (int px_ = 0; px_ < 5; ++px_)                              \
                acc[py_ * 5 + px_] += row_[2*px_ + v_] * wv_;                \
            }                                                                \
          }                                                                  \
        }                                                                    \
      }                                                                      \
    } }

// block = 768 (12 waves), LDS 160.9KB -> 1 WG/CU = 3 waves/SIMD.
// VGPR: the launch-bounds/waves_per_eu knobs are a dead end -- with DYNAMIC
// LDS the compiler's occupancy heuristic can't see the 1-WG/CU limit and pins
// the grant at ~84 regardless of bounds ((768,1) and (768,2) both -> 84; R8/R9
// spilled 5 GB). amdgpu_num_vgpr(168) requests the budget DIRECTLY:
// 168*3 = 504 <= 512 keeps 3 waves/SIMD, and R7's ~113-reg conv2 live set
// (which spilled ~50MB/dispatch at 84) fits with headroom. If VGPR_Count still
// reads 84, the knob is ignored and all future work stays within 84.
// Pipeline (5 barriers/step), R7 structure:
//   step top : wave 0 runs PHASE 6 of t-1; waves 1-11 conv1(t), 1 row each
//              (waves 9-11 take rows 11-13 as a second row)
//   barrier B: conv2 on all 12 waves, single-visit ic split; flag reads are
//              HOISTED to bitmasks and ic0's weight load issues BEFORE them
//              (weights are flag-independent), overlapping the two latencies.
//   barrier C: phase 4 reduce/LIF/list
//   barrier D: phase 5 fc1 gather + XT(t+1) commit
//   barrier E: next step
__global__ __attribute__((amdgpu_flat_work_group_size(768, 768),
                          amdgpu_num_vgpr(168)))
void snn_kernel(
    const float* __restrict__ x,
    const float* __restrict__ bn1_gamma, const float* __restrict__ bn1_beta,
    const float* __restrict__ bn1_mean,  const float* __restrict__ bn1_var,
    const float* __restrict__ bn2_gamma, const float* __restrict__ bn2_beta,
    const float* __restrict__ bn2_mean,  const float* __restrict__ bn2_var,
    const float* __restrict__ beta_c1_raw, const float* __restrict__ beta_c2_raw,
    const float* __restrict__ alpha_raw, const float* __restrict__ rho_raw,
    const float* __restrict__ beta_a_p,  const float* __restrict__ fc_out_w,
    const float* __restrict__ beta_out_p,
    const float* __restrict__ ws, float* __restrict__ out)
{
  extern __shared__ float sm[];
  int* listI = (int*)&sm[L_LIST];
  int* cntI  = (int*)&sm[L_CNT];
  const int tid = threadIdx.x, wave = tid >> 6, lane = tid & 63;
  const int b = blockIdx.x;

  // one-time state zero-init + param staging
  for (int i = tid; i < 6272; i += NT) sm[L_VC1 + i] = 0.f;
  for (int i = tid; i < 1600; i += NT) sm[L_VC2 + i] = 0.f;
  if (tid < 256) {
    sm[L_FCP + tid]       = 1.f / (1.f + expf(-alpha_raw[tid]));
    sm[L_FCP + 256 + tid] = 1.f / (1.f + expf(-rho_raw[tid]));
    sm[L_FCP + 512 + tid] = beta_a_p[tid];
    sm[L_FCS + tid] = 0.f;
    sm[L_FCS + 256 + tid] = 0.f;
    sm[L_FCS + 512 + tid] = 0.f;
  }
  if (tid < 64) {
    float s2 = bn2_gamma[tid] / sqrtf(bn2_var[tid] + 1e-5f);
    sm[L_BN2 + tid]       = s2;
    sm[L_BN2 + 64 + tid]  = bn2_beta[tid] - bn2_mean[tid] * s2;
    sm[L_BN2 + 128 + tid] = 1.f / (1.f + expf(-beta_c2_raw[tid]));
  }

  // conv1 lane mapping: lane = oc*2 + ic
  const int oc1 = lane >> 1, ic1 = lane & 1;
  const float s1v  = bn1_gamma[oc1] / sqrtf(bn1_var[oc1] + 1e-5f);
  const float sh1v = bn1_beta[oc1] - bn1_mean[oc1] * s1v;
  const float b1v  = 1.f / (1.f + expf(-beta_c1_raw[oc1]));
  const float beta_o = 1.f / (1.f + expf(-beta_out_p[0]));

  // conv1 weights: persistent in registers (36 regs)
  float w1r[36];
  #pragma unroll
  for (int j = 0; j < 36; ++j) w1r[j] = ws[WS_W1F + j * 64 + lane];

  float v_out = 0.f, o_sum = 0.f;  // wave0, lane<11

  const float* xbase = x + (size_t)b * T_STEPS * 2048;
  const float* w2f  = ws + WS_W2F;
  const float* fc1T = ws + WS_FC1T;

  // prologue: load+commit x0, prefetch x1
  float4 xpre;
  if (tid < 512) {
    float4 x0 = ((const float4*)xbase)[tid];
    *(float4*)&sm[L_XT + (tid >> 8) * 1040 + ((tid & 255) << 2)] = x0;
    int tn = (T_STEPS > 1) ? 1 : 0;
    xpre = ((const float4*)(xbase + tn * 2048))[tid];
  }

  __syncthreads();

  for (int t = 0; t < T_STEPS; ++t) {
    // ---- phase 2 region: wave 0 phase6(t-1); waves 1-11 conv1(t) ----
    if (wave == 0) {
      if (t > 0) {
        float sk[4];
        #pragma unroll
        for (int k = 0; k < 4; ++k) {
          int j = lane + 64 * k;
          float I = 0.f;
          #pragma unroll
          for (int h2 = 0; h2 < 12; ++h2) I += sm[L_IPART2 + h2 * 256 + j];
          float al = sm[L_FCP + j], rh = sm[L_FCP + 256 + j], ba = sm[L_FCP + 512 + j];
          float vf = sm[L_FCS + j], af = sm[L_FCS + 256 + j], sp0 = sm[L_FCS + 512 + j];
          af = rh * af + (1.f - rh) * sp0;
          float v = al * vf + (1.f - al) * I;
          float sp = (v > 1.f + ba * af) ? 1.f : 0.f;
          sm[L_FCS + j] = v * (1.f - sp);
          sm[L_FCS + 256 + j] = af;
          sm[L_FCS + 512 + j] = sp;
          sk[k] = sp;
        }
        const float4* wop = ((const float4*)(ws + WS_WOUTP)) + lane;
        float p[11];
        #pragma unroll
        for (int o = 0; o < 11; ++o) {
          float4 f = wop[o * 64];          // coalesced, L2-hot
          p[o] = sk[0] * f.x + sk[1] * f.y + sk[2] * f.z + sk[3] * f.w;
        }
        #pragma unroll
        for (int m = 1; m < 64; m <<= 1)
          #pragma unroll
          for (int o = 0; o < 11; ++o) p[o] += __shfl_xor(p[o], m);
        float Isel = p[0];
        #pragma unroll
        for (int o = 1; o < 11; ++o) Isel = (lane == o) ? p[o] : Isel;
        if (lane < 11) {
          v_out = beta_o * v_out + (1.f - beta_o) * Isel;
          o_sum += v_out;
        }
      }
      if (lane == 0) *cntI = 0;
    } else {
      // conv1 rows: waves 1-11 -> rows 0-10; waves 9-11 also rows 11-13
      for (int rr = 0; rr < 2; ++rr) {
        int py = (rr == 0) ? (wave - 1) : ((wave >= 9) ? wave + 2 : -1);
        if (py >= 0) {
          float acc[14];
          #pragma unroll
          for (int p = 0; p < 14; ++p) acc[p] = 0.f;
          const float* xr = &sm[L_XT + ic1 * 1040 + py * 64];
          #pragma unroll
          for (int r = 0; r < 6; ++r) {
            float row[32];
            const float4* rp = (const float4*)&xr[r * 32];
            #pragma unroll
            for (int q = 0; q < 8; ++q) {
              float4 f = rp[q];
              row[4*q] = f.x; row[4*q+1] = f.y; row[4*q+2] = f.z; row[4*q+3] = f.w;
            }
            #pragma unroll
            for (int v = 0; v < 6; ++v) {
              float wv = w1r[r * 6 + v];
              #pragma unroll
              for (int px = 0; px < 14; ++px) acc[px] += row[2*px + v] * wv;
            }
          }
          #pragma unroll
          for (int px = 0; px < 14; ++px) acc[px] += __shfl_xor(acc[px], 1);
          if (ic1 == 0) {
            float flag = 0.f;
            #pragma unroll
            for (int px = 0; px < 14; ++px) {
              float c = acc[px] * s1v + sh1v;
              const int vidx = L_VC1 + (py * 14 + px) * 32 + oc1;
              float vold = sm[vidx];
              float v = b1v * vold + (1.f - b1v) * c;
              float s = (v > 1.f) ? 1.f : 0.f;
              sm[vidx] = v * (1.f - s);
              sm[L_SPK1 + oc1 * 228 + py * 16 + px] = s;
              flag += s;
            }
            sm[L_FLAG + oc1 * 14 + py] = flag;
          }
        }
      }
    }
    __syncthreads();                                     // barrier B

    // ---- phase 3: conv2, 12 waves, single weight buffer.
    //      ic0's (flag-independent) weight load issues BEFORE the flag reads,
    //      so L2 weight latency overlaps LDS flag latency. ----
    {
      const bool three = (wave < 8);
      const int ic0_ = three ? wave : (16 + wave);
      const int icst = three ? 8 : 4;
      const int ic1_ = ic0_ + icst;
      const int ic2_ = ic0_ + 2 * icst;   // only used when three

      float w[36];
      LOADW(w, ic0_)                       // eager: in flight during mask reads

      // hoist flag reads -> 14-bit masks (breaks flag->load dependency)
      unsigned m0 = 0, m1 = 0, m2 = 0;
      {
        const float* f0 = &sm[L_FLAG + ic0_ * 14];
        const float* f1 = &sm[L_FLAG + ic1_ * 14];
        #pragma unroll
        for (int iy = 0; iy < 14; ++iy) {
          m0 |= (f0[iy] != 0.f) ? (1u << iy) : 0u;
          m1 |= (f1[iy] != 0.f) ? (1u << iy) : 0u;
        }
        if (three) {
          const float* f2 = &sm[L_FLAG + ic2_ * 14];
          #pragma unroll
          for (int iy = 0; iy < 14; ++iy)
            m2 |= (f2[iy] != 0.f) ? (1u << iy) : 0u;
        }
      }

      float acc[25];
      #pragma unroll
      for (int p = 0; p < 25; ++p) acc[p] = 0.f;

      if (m0) COMPW(w, ic0_, m0)
      if (m1) { LOADW(w, ic1_) COMPW(w, ic1_, m1) }
      if (three && m2) { LOADW(w, ic2_) COMPW(w, ic2_, m2) }

      #pragma unroll
      for (int p = 0; p < 25; ++p) sm[L_RED + wave * 1600 + lane * 25 + p] = acc[p];
    }
    __syncthreads();                                     // barrier C

    // ---- phase 4: reduce 12 buffers + BN + LIF -> spike list ----
    {
      #pragma unroll
      for (int k = 0; k < 3; ++k) {
        int n = tid + NT * k;
        float s = 0.f;
        if (n < 1600) {
          float ssum = 0.f;
          #pragma unroll
          for (int wv = 0; wv < 12; ++wv) ssum += sm[L_RED + wv * 1600 + n];
          int oc = n / 25;
          float c2 = ssum * sm[L_BN2 + oc] + sm[L_BN2 + 64 + oc];
          float b2 = sm[L_BN2 + 128 + oc];
          const int vidx = L_VC2 + n;
          float vold = sm[vidx];
          float v = b2 * vold + (1.f - b2) * c2;
          s = (v > 1.f) ? 1.f : 0.f;
          sm[vidx] = v * (1.f - s);
        }
        unsigned long long mask = __ballot(s > 0.f);
        if (mask) {
          int base = 0;
          if (lane == 0) base = atomicAdd(cntI, __popcll(mask));
          base = __shfl(base, 0);
          if (s > 0.f) {
            int pos = __popcll(mask & ((1ull << lane) - 1ull));
            listI[base + pos] = n;
          }
        }
      }
    }
    __syncthreads();                                     // barrier D

    // ---- phase 5: fc1 sparse gather (12-way, 4 accs) + XT(t+1) commit ----
    {
      if (tid < 512) {
        *(float4*)&sm[L_XT + (tid >> 8) * 1040 + ((tid & 255) << 2)] = xpre;
        int tn = (t + 2 < T_STEPS) ? t + 2 : T_STEPS - 1;
        xpre = ((const float4*)(xbase + tn * 2048))[tid];
      }
      const int nn = *cntI;
      const float4* fc4 = (const float4*)fc1T;
      float4 a0 = {0.f,0.f,0.f,0.f}, a1 = {0.f,0.f,0.f,0.f};
      float4 a2 = {0.f,0.f,0.f,0.f}, a3 = {0.f,0.f,0.f,0.f};
      int i = wave;
      for (; i + 36 < nn; i += 48) {
        int k0 = listI[i], k1 = listI[i + 12], k2 = listI[i + 24], k3 = listI[i + 36];
        float4 f0 = fc4[k0 * 64 + lane];
        float4 f1 = fc4[k1 * 64 + lane];
        float4 f2 = fc4[k2 * 64 + lane];
        float4 f3 = fc4[k3 * 64 + lane];
        a0.x += f0.x; a0.y += f0.y; a0.z += f0.z; a0.w += f0.w;
        a1.x += f1.x; a1.y += f1.y; a1.z += f1.z; a1.w += f1.w;
        a2.x += f2.x; a2.y += f2.y; a2.z += f2.z; a2.w += f2.w;
        a3.x += f3.x; a3.y += f3.y; a3.z += f3.z; a3.w += f3.w;
      }
      for (; i < nn; i += 12) {
        int k = listI[i];
        float4 f = fc4[k * 64 + lane];
        a0.x += f.x; a0.y += f.y; a0.z += f.z; a0.w += f.w;
      }
      a0.x += a1.x + a2.x + a3.x;
      a0.y += a1.y + a2.y + a3.y;
      a0.z += a1.z + a2.z + a3.z;
      a0.w += a1.w + a2.w + a3.w;
      ((float4*)&sm[L_IPART2])[wave * 64 + lane] = a0;   // aliases RED[0..3072)
    }
    __syncthreads();                                     // barrier E
    // phase 6 for this t runs at the top of the next iteration (wave 0).
  }

  // epilogue: phase 6 for t = T_STEPS-1
  if (wave == 0) {
    float sk[4];
    #pragma unroll
    for (int k = 0; k < 4; ++k) {
      int j = lane + 64 * k;
      float I = 0.f;
      #pragma unroll
      for (int h2 = 0; h2 < 12; ++h2) I += sm[L_IPART2 + h2 * 256 + j];
      float al = sm[L_FCP + j], rh = sm[L_FCP + 256 + j], ba = sm[L_FCP + 512 + j];
      float vf = sm[L_FCS + j], af = sm[L_FCS + 256 + j], sp0 = sm[L_FCS + 512 + j];
      af = rh * af + (1.f - rh) * sp0;
      float v = al * vf + (1.f - al) * I;
      float sp = (v > 1.f + ba * af) ? 1.f : 0.f;
      sk[k] = sp;
    }
    const float4* wop = ((const float4*)(ws + WS_WOUTP)) + lane;
    float p[11];
    #pragma unroll
    for (int o = 0; o < 11; ++o) {
      float4 f = wop[o * 64];
      p[o] = sk[0] * f.x + sk[1] * f.y + sk[2] * f.z + sk[3] * f.w;
    }
    #pragma unroll
    for (int m = 1; m < 64; m <<= 1)
      #pragma unroll
      for (int o = 0; o < 11; ++o) p[o] += __shfl_xor(p[o], m);
    float Isel = p[0];
    #pragma unroll
    for (int o = 1; o < 11; ++o) Isel = (lane == o) ? p[o] : Isel;
    if (lane < 11) {
      v_out = beta_o * v_out + (1.f - beta_o) * Isel;
      o_sum += v_out;
      out[b * 11 + lane] = o_sum * (1.f / T_STEPS);
    }
  }
}

extern "C" void kernel_launch(void* const* d_in, const int* in_sizes, int n_in,
                              void* d_out, int out_size, void* d_ws, size_t ws_size,
                              hipStream_t stream) {
  const float* x            = (const float*)d_in[0];
  const float* conv1_w      = (const float*)d_in[1];
  const float* bn1_gamma    = (const float*)d_in[2];
  const float* bn1_beta     = (const float*)d_in[3];
  const float* bn1_mean     = (const float*)d_in[4];
  const float* bn1_var      = (const float*)d_in[5];
  const float* conv2_w      = (const float*)d_in[6];
  const float* bn2_gamma    = (const float*)d_in[7];
  const float* bn2_beta     = (const float*)d_in[8];
  const float* bn2_mean     = (const float*)d_in[9];
  const float* bn2_var      = (const float*)d_in[10];
  const float* beta_c1_raw  = (const float*)d_in[11];
  const float* beta_c2_raw  = (const float*)d_in[12];
  const float* fc1_w        = (const float*)d_in[13];
  const float* alpha_raw    = (const float*)d_in[14];
  const float* rho_raw      = (const float*)d_in[15];
  const float* beta_a_p     = (const float*)d_in[16];
  const float* fc_out_w     = (const float*)d_in[17];
  const float* beta_out_p   = (const float*)d_in[18];
  float* ws  = (float*)d_ws;
  float* outp = (float*)d_out;

  (void)in_sizes; (void)n_in; (void)out_size; (void)ws_size;

  hipFuncSetAttribute((const void*)snn_kernel,
                      hipFuncAttributeMaxDynamicSharedMemorySize, SMEM_BYTES);

  prep_kernel<<<dim3((WS_TOTAL + 255) / 256), dim3(256), 0, stream>>>(
      conv1_w, conv2_w, fc1_w, fc_out_w, ws);

  snn_kernel<<<dim3(128), dim3(NT), SMEM_BYTES, stream>>>(
      x, bn1_gamma, bn1_beta, bn1_mean, bn1_var,
      bn2_gamma, bn2_beta, bn2_mean, bn2_var,
      beta_c1_raw, beta_c2_raw, alpha_raw, rho_raw, beta_a_p,
      fc_out_w, beta_out_p, ws, outp);
}

// Round 12
// 635.644 us; speedup vs baseline: 5.0086x; 3.0542x over previous
//
#include <hip/hip_runtime.h>
#include <math.h>

#define T_STEPS 50
#define NT 768

// workspace layout (float offsets)
#define WS_FC1T 0          // 1600*256 = 409600 : fc1_w transposed [k][j]
#define WS_W2F  409600     // 32*2*5*64*4 = 81920 : folded conv2, PARITY layout
                           //   (((ic*2+par)*5+q)*64+oc)*4+r ; j2=4q+r in [0,18):
                           //   u = 2*(j2/6)+par, v = j2%6 ; j2 in {18,19} = 0 pad
#define WS_W1F  491520     // 36*64 = 2304 : folded conv1 [j][oc*2+ic]
#define WS_WOUTP 493824    // 2816 : fc_out packed [(o*64+lane)*4+k]
#define WS_TOTAL 496640

// LDS layout (float offsets). 40464 floats = 161856 B <= 163840 (160 KiB).
// Aliases (all barrier-proven):
//  - IPART2 aliases RED bufs 0-1 (RED live phase3..4; IPART2 live phase5..
//    next-step phase6 which ends before barrier B -> before next RED write).
//  - XT aliases RED bufs 8-9 (XT live phase5(t)..phase2(t+1); RED live
//    phase3..phase4 -- disjoint by barriers B and D).
#define L_SPK1  0          // 7296 : 32 planes, stride 228
#define L_RED   7296       // 19200 : 12 conv2 partial buffers
#define L_IPART2 L_RED     // 3072 alias : fc1 partials, 12 waves x 256
#define L_XT    20096      // 2080 alias (RED+12800) : x_t tile, ic-stride 1040
#define L_LIST  26496      // 1600 (ints)
#define L_FLAG  28096      // 448
#define L_CNT   28544      // 16
#define L_VC1   28560      // 6272 : conv1 membrane, [py*14+px]*32 + oc
#define L_VC2   34832      // 1600
#define L_BN2   36432      // 192 : s2 | sh2 | b2
#define L_FCP   36624      // 768 : alpha | rho | beta_a
#define L_FCS   37392      // 768 : vfc | afc | spf
#define L_W1    38160      // 2304 : conv1 folded weights [j][64] (was 36 VGPRs!)
#define L_TOTALF 40464
#define SMEM_BYTES (L_TOTALF * 4)

__global__ void prep_kernel(const float* __restrict__ conv1_w,
                            const float* __restrict__ conv2_w,
                            const float* __restrict__ fc1_w,
                            const float* __restrict__ fc_out_w,
                            float* __restrict__ ws) {
  int i = blockIdx.x * blockDim.x + threadIdx.x;
  if (i < 409600) {
    int k = i >> 8, j = i & 255;
    ws[WS_FC1T + i] = fc1_w[j * 1600 + k];
  } else if (i < 491520) {
    // parity layout: i2 = (((ic*2+par)*5+q)*64 + oc)*4 + r
    int i2 = i - 409600;
    int r  = i2 & 3;
    int s_ = i2 >> 2;
    int oc = s_ & 63;
    int m  = s_ >> 6;        // (ic*2+par)*5 + q
    int q  = m % 5;
    int par = (m / 5) & 1;
    int ic = m / 10;
    int j2 = q * 4 + r;      // 0..19
    float val = 0.f;
    if (j2 < 18) {
      int u = 2 * (j2 / 6) + par;
      int v = j2 % 6;
      float s = 0.f;
      for (int dy = 0; dy < 2; ++dy) {
        int ky = u - dy; if (ky < 0 || ky > 4) continue;
        for (int dx = 0; dx < 2; ++dx) {
          int kx = v - dx; if (kx < 0 || kx > 4) continue;
          s += conv2_w[((oc * 32 + ic) * 5 + ky) * 5 + kx];
        }
      }
      val = 0.25f * s;
    }
    ws[WS_W2F + i2] = val;
  } else if (i < 493824) {
    int i3 = i - 491520;
    int jj = i3 >> 6, l = i3 & 63, oc = l >> 1, ic = l & 1, u = jj / 6, v = jj % 6;
    float s = 0.f;
    for (int dy = 0; dy < 2; ++dy) {
      int ky = u - dy; if (ky < 0 || ky > 4) continue;
      for (int dx = 0; dx < 2; ++dx) {
        int kx = v - dx; if (kx < 0 || kx > 4) continue;
        s += conv1_w[((oc * 2 + ic) * 5 + ky) * 5 + kx];
      }
    }
    ws[WS_W1F + i3] = 0.25f * s;
  } else if (i < WS_TOTAL) {
    // fc_out packed for per-lane float4 loads in phase 6
    int i4 = i - 493824;
    int k  = i4 & 3;
    int s_ = i4 >> 2;
    int ln = s_ & 63;
    int o  = s_ >> 6;
    ws[WS_WOUTP + i4] = fc_out_w[o * 256 + k * 64 + ln];
  }
}

// conv2 parity weight load: 5 coalesced 1KB wave-loads into w20.
#define LOADW5(WD, IC, PAR) {                                                \
    const float4* wp_ = ((const float4*)w2f) + (((IC) * 2 + (PAR)) * 5) * 64 + lane; \
    _Pragma("unroll")                                                        \
    for (int q_ = 0; q_ < 5; ++q_) {                                         \
      float4 f_ = wp_[q_ * 64];                                              \
      WD[4*q_] = f_.x; WD[4*q_+1] = f_.y; WD[4*q_+2] = f_.z; WD[4*q_+3] = f_.w; \
    } }

// conv2 compute for one ic, one parity. MM bit k <-> row iy = 2k+PAR.
// Row iy only uses taps u = 2*uh+PAR (uh = 0..2), py = k - uh.
// Each live row read ONCE; weight live set is 20 regs (was 36).
#define COMP_PAR(WD, IC, MM, PAR) {                                          \
    const float* srow_ = &sm[L_SPK1 + (IC) * 228 + (PAR) * 16];              \
    _Pragma("unroll")                                                        \
    for (int k_ = 0; k_ < 7; ++k_) {                                         \
      if ((MM) & (1u << k_)) {                                               \
        float row_[16];                                                      \
        const float4* rp_ = (const float4*)&srow_[k_ * 32];                  \
        _Pragma("unroll")                                                    \
        for (int q_ = 0; q_ < 4; ++q_) {                                     \
          float4 f_ = rp_[q_];                                               \
          row_[4*q_] = f_.x; row_[4*q_+1] = f_.y; row_[4*q_+2] = f_.z; row_[4*q_+3] = f_.w; \
        }                                                                    \
        _Pragma("unroll")                                                    \
        for (int uh_ = 0; uh_ < 3; ++uh_) {                                  \
          const int py_ = k_ - uh_;                                          \
          if (py_ >= 0 && py_ <= 4) {                                        \
            _Pragma("unroll")                                                \
            for (int v_ = 0; v_ < 6; ++v_) {                                 \
              float wv_ = WD[uh_ * 6 + v_];                                  \
              _Pragma("unroll")                                              \
              for (int px_ = 0; px_ < 5; ++px_)                              \
                acc[py_ * 5 + px_] += row_[2*px_ + v_] * wv_;                \
            }                                                                \
          }                                                                  \
        }                                                                    \
      }                                                                      \
    } }

// block = 768 (12 waves), LDS 161.9KB -> 1 WG/CU = 3 waves/SIMD.
// VGPR: the grant is pinned at 84 for this shape (launch_bounds arg2 1/2,
// waves_per_eu, amdgpu_num_vgpr ALL ignored -- 4 experiments, R2/R4/R9/R10).
// So the kernel is engineered to FIT 84: conv1 weights moved to LDS (-36
// persistent), conv2 weights parity-split to 20 regs (-16 in hot phase).
// Peak conv2 live ~= acc25 + w20 + row16 + masks/addr ~= 75 <= 84 -> no spill.
// Pipeline (5 barriers/step), R7 structure:
//   step top : wave 0 runs PHASE 6 of t-1; waves 1-11 conv1(t)
//   barrier B: conv2 (12 waves, single-visit ic split, per-parity flag gating)
//   barrier C: phase 4 reduce/LIF/list
//   barrier D: phase 5 fc1 gather + XT(t+1) commit (XT aliases RED 8-9)
//   barrier E: next step
__global__ __launch_bounds__(NT, 2) void snn_kernel(
    const float* __restrict__ x,
    const float* __restrict__ bn1_gamma, const float* __restrict__ bn1_beta,
    const float* __restrict__ bn1_mean,  const float* __restrict__ bn1_var,
    const float* __restrict__ bn2_gamma, const float* __restrict__ bn2_beta,
    const float* __restrict__ bn2_mean,  const float* __restrict__ bn2_var,
    const float* __restrict__ beta_c1_raw, const float* __restrict__ beta_c2_raw,
    const float* __restrict__ alpha_raw, const float* __restrict__ rho_raw,
    const float* __restrict__ beta_a_p,  const float* __restrict__ fc_out_w,
    const float* __restrict__ beta_out_p,
    const float* __restrict__ ws, float* __restrict__ out)
{
  extern __shared__ float sm[];
  int* listI = (int*)&sm[L_LIST];
  int* cntI  = (int*)&sm[L_CNT];
  const int tid = threadIdx.x, wave = tid >> 6, lane = tid & 63;
  const int b = blockIdx.x;

  // one-time state zero-init + param/weight staging
  for (int i = tid; i < 6272; i += NT) sm[L_VC1 + i] = 0.f;
  for (int i = tid; i < 1600; i += NT) sm[L_VC2 + i] = 0.f;
  for (int i = tid; i < 2304; i += NT) sm[L_W1 + i] = ws[WS_W1F + i];
  if (tid < 256) {
    sm[L_FCP + tid]       = 1.f / (1.f + expf(-alpha_raw[tid]));
    sm[L_FCP + 256 + tid] = 1.f / (1.f + expf(-rho_raw[tid]));
    sm[L_FCP + 512 + tid] = beta_a_p[tid];
    sm[L_FCS + tid] = 0.f;
    sm[L_FCS + 256 + tid] = 0.f;
    sm[L_FCS + 512 + tid] = 0.f;
  }
  if (tid < 64) {
    float s2 = bn2_gamma[tid] / sqrtf(bn2_var[tid] + 1e-5f);
    sm[L_BN2 + tid]       = s2;
    sm[L_BN2 + 64 + tid]  = bn2_beta[tid] - bn2_mean[tid] * s2;
    sm[L_BN2 + 128 + tid] = 1.f / (1.f + expf(-beta_c2_raw[tid]));
  }

  // conv1 lane mapping: lane = oc*2 + ic
  const int oc1 = lane >> 1, ic1 = lane & 1;
  const float s1v  = bn1_gamma[oc1] / sqrtf(bn1_var[oc1] + 1e-5f);
  const float sh1v = bn1_beta[oc1] - bn1_mean[oc1] * s1v;
  const float b1v  = 1.f / (1.f + expf(-beta_c1_raw[oc1]));
  const float beta_o = 1.f / (1.f + expf(-beta_out_p[0]));

  float v_out = 0.f, o_sum = 0.f;  // wave0, lane<11

  const float* xbase = x + (size_t)b * T_STEPS * 2048;
  const float* w2f  = ws + WS_W2F;
  const float* fc1T = ws + WS_FC1T;
  const float* smw1 = &sm[L_W1];

  // prologue: load+commit x0, prefetch x1 (XT aliases RED 8-9; no RED use yet)
  float4 xpre;
  if (tid < 512) {
    float4 x0 = ((const float4*)xbase)[tid];
    *(float4*)&sm[L_XT + (tid >> 8) * 1040 + ((tid & 255) << 2)] = x0;
    int tn = (T_STEPS > 1) ? 1 : 0;
    xpre = ((const float4*)(xbase + tn * 2048))[tid];
  }

  __syncthreads();

  for (int t = 0; t < T_STEPS; ++t) {
    // ---- phase 2 region: wave 0 phase6(t-1); waves 1-11 conv1(t) ----
    if (wave == 0) {
      if (t > 0) {
        float sk[4];
        #pragma unroll
        for (int k = 0; k < 4; ++k) {
          int j = lane + 64 * k;
          float I = 0.f;
          #pragma unroll
          for (int h2 = 0; h2 < 12; ++h2) I += sm[L_IPART2 + h2 * 256 + j];
          float al = sm[L_FCP + j], rh = sm[L_FCP + 256 + j], ba = sm[L_FCP + 512 + j];
          float vf = sm[L_FCS + j], af = sm[L_FCS + 256 + j], sp0 = sm[L_FCS + 512 + j];
          af = rh * af + (1.f - rh) * sp0;
          float v = al * vf + (1.f - al) * I;
          float sp = (v > 1.f + ba * af) ? 1.f : 0.f;
          sm[L_FCS + j] = v * (1.f - sp);
          sm[L_FCS + 256 + j] = af;
          sm[L_FCS + 512 + j] = sp;
          sk[k] = sp;
        }
        const float4* wop = ((const float4*)(ws + WS_WOUTP)) + lane;
        float p[11];
        #pragma unroll
        for (int o = 0; o < 11; ++o) {
          float4 f = wop[o * 64];          // coalesced, L2-hot
          p[o] = sk[0] * f.x + sk[1] * f.y + sk[2] * f.z + sk[3] * f.w;
        }
        #pragma unroll
        for (int m = 1; m < 64; m <<= 1)
          #pragma unroll
          for (int o = 0; o < 11; ++o) p[o] += __shfl_xor(p[o], m);
        float Isel = p[0];
        #pragma unroll
        for (int o = 1; o < 11; ++o) Isel = (lane == o) ? p[o] : Isel;
        if (lane < 11) {
          v_out = beta_o * v_out + (1.f - beta_o) * Isel;
          o_sum += v_out;
        }
      }
      if (lane == 0) *cntI = 0;
    } else {
      // conv1 rows: waves 1-11 -> rows 0-10; waves 9-11 also rows 11-13.
      // Weights read from LDS [j][64] (lane-consecutive, conflict-free).
      for (int rr = 0; rr < 2; ++rr) {
        int py = (rr == 0) ? (wave - 1) : ((wave >= 9) ? wave + 2 : -1);
        if (py >= 0) {
          float acc[14];
          #pragma unroll
          for (int p = 0; p < 14; ++p) acc[p] = 0.f;
          const float* xr = &sm[L_XT + ic1 * 1040 + py * 64];
          #pragma unroll
          for (int r = 0; r < 6; ++r) {
            float row[32];
            const float4* rp = (const float4*)&xr[r * 32];
            #pragma unroll
            for (int q = 0; q < 8; ++q) {
              float4 f = rp[q];
              row[4*q] = f.x; row[4*q+1] = f.y; row[4*q+2] = f.z; row[4*q+3] = f.w;
            }
            #pragma unroll
            for (int v = 0; v < 6; ++v) {
              float wv = smw1[(r * 6 + v) * 64 + lane];
              #pragma unroll
              for (int px = 0; px < 14; ++px) acc[px] += row[2*px + v] * wv;
            }
          }
          #pragma unroll
          for (int px = 0; px < 14; ++px) acc[px] += __shfl_xor(acc[px], 1);
          if (ic1 == 0) {
            float flag = 0.f;
            #pragma unroll
            for (int px = 0; px < 14; ++px) {
              float c = acc[px] * s1v + sh1v;
              const int vidx = L_VC1 + (py * 14 + px) * 32 + oc1;
              float vold = sm[vidx];
              float v = b1v * vold + (1.f - b1v) * c;
              float s = (v > 1.f) ? 1.f : 0.f;
              sm[vidx] = v * (1.f - s);
              sm[L_SPK1 + oc1 * 228 + py * 16 + px] = s;
              flag += s;
            }
            sm[L_FLAG + oc1 * 14 + py] = flag;
          }
        }
      }
    }
    __syncthreads();                                     // barrier B

    // ---- phase 3: conv2, 12 waves, parity-split taps (w live set = 20) ----
    {
      const bool three = (wave < 8);
      const int ic0_ = three ? wave : (16 + wave);
      const int icst = three ? 8 : 4;
      const int nic  = three ? 3 : 2;
      float acc[25];
      #pragma unroll
      for (int p = 0; p < 25; ++p) acc[p] = 0.f;
      for (int ib = 0; ib < nic; ++ib) {
        const int ic = ic0_ + ib * icst;
        const float* fl = &sm[L_FLAG + ic * 14];
        unsigned mE = 0, mO = 0;
        #pragma unroll
        for (int k = 0; k < 7; ++k) {
          mE |= (fl[2*k]     != 0.f) ? (1u << k) : 0u;
          mO |= (fl[2*k + 1] != 0.f) ? (1u << k) : 0u;
        }
        float w20[20];
        if (mE) { LOADW5(w20, ic, 0) COMP_PAR(w20, ic, mE, 0) }
        if (mO) { LOADW5(w20, ic, 1) COMP_PAR(w20, ic, mO, 1) }
      }
      #pragma unroll
      for (int p = 0; p < 25; ++p) sm[L_RED + wave * 1600 + lane * 25 + p] = acc[p];
    }
    __syncthreads();                                     // barrier C

    // ---- phase 4: reduce 12 buffers + BN + LIF -> spike list ----
    {
      #pragma unroll
      for (int k = 0; k < 3; ++k) {
        int n = tid + NT * k;
        float s = 0.f;
        if (n < 1600) {
          float ssum = 0.f;
          #pragma unroll
          for (int wv = 0; wv < 12; ++wv) ssum += sm[L_RED + wv * 1600 + n];
          int oc = n / 25;
          float c2 = ssum * sm[L_BN2 + oc] + sm[L_BN2 + 64 + oc];
          float b2 = sm[L_BN2 + 128 + oc];
          const int vidx = L_VC2 + n;
          float vold = sm[vidx];
          float v = b2 * vold + (1.f - b2) * c2;
          s = (v > 1.f) ? 1.f : 0.f;
          sm[vidx] = v * (1.f - s);
        }
        unsigned long long mask = __ballot(s > 0.f);
        if (mask) {
          int base = 0;
          if (lane == 0) base = atomicAdd(cntI, __popcll(mask));
          base = __shfl(base, 0);
          if (s > 0.f) {
            int pos = __popcll(mask & ((1ull << lane) - 1ull));
            listI[base + pos] = n;
          }
        }
      }
    }
    __syncthreads();                                     // barrier D

    // ---- phase 5: fc1 sparse gather (12-way, 4 accs) + XT(t+1) commit ----
    {
      if (tid < 512) {
        *(float4*)&sm[L_XT + (tid >> 8) * 1040 + ((tid & 255) << 2)] = xpre;
        int tn = (t + 2 < T_STEPS) ? t + 2 : T_STEPS - 1;
        xpre = ((const float4*)(xbase + tn * 2048))[tid];
      }
      const int nn = *cntI;
      const float4* fc4 = (const float4*)fc1T;
      float4 a0 = {0.f,0.f,0.f,0.f}, a1 = {0.f,0.f,0.f,0.f};
      float4 a2 = {0.f,0.f,0.f,0.f}, a3 = {0.f,0.f,0.f,0.f};
      int i = wave;
      for (; i + 36 < nn; i += 48) {
        int k0 = listI[i], k1 = listI[i + 12], k2 = listI[i + 24], k3 = listI[i + 36];
        float4 f0 = fc4[k0 * 64 + lane];
        float4 f1 = fc4[k1 * 64 + lane];
        float4 f2 = fc4[k2 * 64 + lane];
        float4 f3 = fc4[k3 * 64 + lane];
        a0.x += f0.x; a0.y += f0.y; a0.z += f0.z; a0.w += f0.w;
        a1.x += f1.x; a1.y += f1.y; a1.z += f1.z; a1.w += f1.w;
        a2.x += f2.x; a2.y += f2.y; a2.z += f2.z; a2.w += f2.w;
        a3.x += f3.x; a3.y += f3.y; a3.z += f3.z; a3.w += f3.w;
      }
      for (; i < nn; i += 12) {
        int k = listI[i];
        float4 f = fc4[k * 64 + lane];
        a0.x += f.x; a0.y += f.y; a0.z += f.z; a0.w += f.w;
      }
      a0.x += a1.x + a2.x + a3.x;
      a0.y += a1.y + a2.y + a3.y;
      a0.z += a1.z + a2.z + a3.z;
      a0.w += a1.w + a2.w + a3.w;
      ((float4*)&sm[L_IPART2])[wave * 64 + lane] = a0;   // aliases RED bufs 0-1
    }
    __syncthreads();                                     // barrier E
    // phase 6 for this t runs at the top of the next iteration (wave 0).
  }

  // epilogue: phase 6 for t = T_STEPS-1
  if (wave == 0) {
    float sk[4];
    #pragma unroll
    for (int k = 0; k < 4; ++k) {
      int j = lane + 64 * k;
      float I = 0.f;
      #pragma unroll
      for (int h2 = 0; h2 < 12; ++h2) I += sm[L_IPART2 + h2 * 256 + j];
      float al = sm[L_FCP + j], rh = sm[L_FCP + 256 + j], ba = sm[L_FCP + 512 + j];
      float vf = sm[L_FCS + j], af = sm[L_FCS + 256 + j], sp0 = sm[L_FCS + 512 + j];
      af = rh * af + (1.f - rh) * sp0;
      float v = al * vf + (1.f - al) * I;
      float sp = (v > 1.f + ba * af) ? 1.f : 0.f;
      sk[k] = sp;
    }
    const float4* wop = ((const float4*)(ws + WS_WOUTP)) + lane;
    float p[11];
    #pragma unroll
    for (int o = 0; o < 11; ++o) {
      float4 f = wop[o * 64];
      p[o] = sk[0] * f.x + sk[1] * f.y + sk[2] * f.z + sk[3] * f.w;
    }
    #pragma unroll
    for (int m = 1; m < 64; m <<= 1)
      #pragma unroll
      for (int o = 0; o < 11; ++o) p[o] += __shfl_xor(p[o], m);
    float Isel = p[0];
    #pragma unroll
    for (int o = 1; o < 11; ++o) Isel = (lane == o) ? p[o] : Isel;
    if (lane < 11) {
      v_out = beta_o * v_out + (1.f - beta_o) * Isel;
      o_sum += v_out;
      out[b * 11 + lane] = o_sum * (1.f / T_STEPS);
    }
  }
}

extern "C" void kernel_launch(void* const* d_in, const int* in_sizes, int n_in,
                              void* d_out, int out_size, void* d_ws, size_t ws_size,
                              hipStream_t stream) {
  const float* x            = (const float*)d_in[0];
  const float* conv1_w      = (const float*)d_in[1];
  const float* bn1_gamma    = (const float*)d_in[2];
  const float* bn1_beta     = (const float*)d_in[3];
  const float* bn1_mean     = (const float*)d_in[4];
  const float* bn1_var      = (const float*)d_in[5];
  const float* conv2_w      = (const float*)d_in[6];
  const float* bn2_gamma    = (const float*)d_in[7];
  const float* bn2_beta     = (const float*)d_in[8];
  const float* bn2_mean     = (const float*)d_in[9];
  const float* bn2_var      = (const float*)d_in[10];
  const float* beta_c1_raw  = (const float*)d_in[11];
  const float* beta_c2_raw  = (const float*)d_in[12];
  const float* fc1_w        = (const float*)d_in[13];
  const float* alpha_raw    = (const float*)d_in[14];
  const float* rho_raw      = (const float*)d_in[15];
  const float* beta_a_p     = (const float*)d_in[16];
  const float* fc_out_w     = (const float*)d_in[17];
  const float* beta_out_p   = (const float*)d_in[18];
  float* ws  = (float*)d_ws;
  float* outp = (float*)d_out;

  (void)in_sizes; (void)n_in; (void)out_size; (void)ws_size;

  hipFuncSetAttribute((const void*)snn_kernel,
                      hipFuncAttributeMaxDynamicSharedMemorySize, SMEM_BYTES);

  prep_kernel<<<dim3((WS_TOTAL + 255) / 256), dim3(256), 0, stream>>>(
      conv1_w, conv2_w, fc1_w, fc_out_w, ws);

  snn_kernel<<<dim3(128), dim3(NT), SMEM_BYTES, stream>>>(
      x, bn1_gamma, bn1_beta, bn1_mean, bn1_var,
      bn2_gamma, bn2_beta, bn2_mean, bn2_var,
      beta_c1_raw, beta_c2_raw, alpha_raw, rho_raw, beta_a_p,
      fc_out_w, beta_out_p, ws, outp);
}

// Round 13
// 557.323 us; speedup vs baseline: 5.7124x; 1.1405x over previous
//
#include <hip/hip_runtime.h>
#include <math.h>

#define T_STEPS 50
#define NT 768

// workspace layout (float offsets)
#define WS_FC1T 0          // 1600*256 = 409600 : fc1_w transposed [k][j]
#define WS_W2F  409600     // 32*2*5*64*4 = 81920 : folded conv2, PARITY layout
                           //   (((ic*2+par)*5+q)*64+oc)*4+r ; j2=4q+r in [0,18):
                           //   u = 2*(j2/6)+par, v = j2%6 ; j2 in {18,19} = 0 pad
#define WS_W1F  491520     // 36*64 = 2304 : folded conv1 [j][oc*2+ic]
#define WS_WOUTP 493824    // 2816 : fc_out packed [(o*64+lane)*4+k]
#define WS_TOTAL 496640

// LDS layout (float offsets). 40464 floats = 161856 B <= 163840 (160 KiB).
// Aliases (all barrier-proven):
//  - IPART2 aliases RED bufs 0-1 (RED live phase3..4; IPART2 live phase5..
//    next-step phase6 which ends before barrier B -> before next RED write).
//  - XT aliases RED bufs 8-9 (XT live phase5(t)..phase2(t+1); RED live
//    phase3..phase4 -- disjoint by barriers B and D).
#define L_SPK1  0          // 7296 : 32 planes, stride 228
#define L_RED   7296       // 19200 : 12 conv2 partial buffers
#define L_IPART2 L_RED     // 3072 alias : fc1 partials, 12 waves x 256
#define L_XT    20096      // 2080 alias (RED+12800) : x_t tile, ic-stride 1040
#define L_LIST  26496      // 1600 (ints)
#define L_FLAG  28096      // 448
#define L_CNT   28544      // 16
#define L_VC1   28560      // 6272 : conv1 membrane, [py*14+px]*32 + oc
#define L_VC2   34832      // 1600
#define L_BN2   36432      // 192 : s2 | sh2 | b2
#define L_FCP   36624      // 768 : alpha | rho | beta_a
#define L_FCS   37392      // 768 : vfc | afc | spf
#define L_W1    38160      // 2304 : conv1 folded weights [j][64]
#define L_TOTALF 40464
#define SMEM_BYTES (L_TOTALF * 4)

__global__ void prep_kernel(const float* __restrict__ conv1_w,
                            const float* __restrict__ conv2_w,
                            const float* __restrict__ fc1_w,
                            const float* __restrict__ fc_out_w,
                            float* __restrict__ ws) {
  int i = blockIdx.x * blockDim.x + threadIdx.x;
  if (i < 409600) {
    int k = i >> 8, j = i & 255;
    ws[WS_FC1T + i] = fc1_w[j * 1600 + k];
  } else if (i < 491520) {
    // parity layout: i2 = (((ic*2+par)*5+q)*64 + oc)*4 + r
    int i2 = i - 409600;
    int r  = i2 & 3;
    int s_ = i2 >> 2;
    int oc = s_ & 63;
    int m  = s_ >> 6;        // (ic*2+par)*5 + q
    int q  = m % 5;
    int par = (m / 5) & 1;
    int ic = m / 10;
    int j2 = q * 4 + r;      // 0..19
    float val = 0.f;
    if (j2 < 18) {
      int u = 2 * (j2 / 6) + par;
      int v = j2 % 6;
      float s = 0.f;
      for (int dy = 0; dy < 2; ++dy) {
        int ky = u - dy; if (ky < 0 || ky > 4) continue;
        for (int dx = 0; dx < 2; ++dx) {
          int kx = v - dx; if (kx < 0 || kx > 4) continue;
          s += conv2_w[((oc * 32 + ic) * 5 + ky) * 5 + kx];
        }
      }
      val = 0.25f * s;
    }
    ws[WS_W2F + i2] = val;
  } else if (i < 493824) {
    int i3 = i - 491520;
    int jj = i3 >> 6, l = i3 & 63, oc = l >> 1, ic = l & 1, u = jj / 6, v = jj % 6;
    float s = 0.f;
    for (int dy = 0; dy < 2; ++dy) {
      int ky = u - dy; if (ky < 0 || ky > 4) continue;
      for (int dx = 0; dx < 2; ++dx) {
        int kx = v - dx; if (kx < 0 || kx > 4) continue;
        s += conv1_w[((oc * 2 + ic) * 5 + ky) * 5 + kx];
      }
    }
    ws[WS_W1F + i3] = 0.25f * s;
  } else if (i < WS_TOTAL) {
    // fc_out packed for per-lane float4 loads in phase 6
    int i4 = i - 493824;
    int k  = i4 & 3;
    int s_ = i4 >> 2;
    int ln = s_ & 63;
    int o  = s_ >> 6;
    ws[WS_WOUTP + i4] = fc_out_w[o * 256 + k * 64 + ln];
  }
}

// conv2 parity weight load: 5 coalesced 1KB wave-loads into w20.
#define LOADW5(WD, IC, PAR) {                                                \
    const float4* wp_ = ((const float4*)w2f) + (((IC) * 2 + (PAR)) * 5) * 64 + lane; \
    _Pragma("unroll")                                                        \
    for (int q_ = 0; q_ < 5; ++q_) {                                         \
      float4 f_ = wp_[q_ * 64];                                              \
      WD[4*q_] = f_.x; WD[4*q_+1] = f_.y; WD[4*q_+2] = f_.z; WD[4*q_+3] = f_.w; \
    } }

// conv2 compute for one ic, one parity. MM bit k <-> row iy = 2k+PAR.
// Row iy only uses taps u = 2*uh+PAR (uh = 0..2), py = k - uh.
// Each live row read ONCE; weight live set is 20 regs.
#define COMP_PAR(WD, IC, MM, PAR) {                                          \
    const float* srow_ = &sm[L_SPK1 + (IC) * 228 + (PAR) * 16];              \
    _Pragma("unroll")                                                        \
    for (int k_ = 0; k_ < 7; ++k_) {                                         \
      if ((MM) & (1u << k_)) {                                               \
        float row_[16];                                                      \
        const float4* rp_ = (const float4*)&srow_[k_ * 32];                  \
        _Pragma("unroll")                                                    \
        for (int q_ = 0; q_ < 4; ++q_) {                                     \
          float4 f_ = rp_[q_];                                               \
          row_[4*q_] = f_.x; row_[4*q_+1] = f_.y; row_[4*q_+2] = f_.z; row_[4*q_+3] = f_.w; \
        }                                                                    \
        _Pragma("unroll")                                                    \
        for (int uh_ = 0; uh_ < 3; ++uh_) {                                  \
          const int py_ = k_ - uh_;                                          \
          if (py_ >= 0 && py_ <= 4) {                                        \
            _Pragma("unroll")                                                \
            for (int v_ = 0; v_ < 6; ++v_) {                                 \
              float wv_ = WD[uh_ * 6 + v_];                                  \
              _Pragma("unroll")                                              \
              for (int px_ = 0; px_ < 5; ++px_)                              \
                acc[py_ * 5 + px_] += row_[2*px_ + v_] * wv_;                \
            }                                                                \
          }                                                                  \
        }                                                                    \
      }                                                                      \
    } }

// block = 768 (12 waves), LDS 161.9KB -> 1 WG/CU = 3 waves/SIMD.
// VGPR: grant pinned at 84 for this shape (4 knob experiments all ignored);
// kernel engineered to FIT: conv1 weights in LDS, conv2 weights parity-split
// to 20 regs. R11 confirmed: WRITE 108->16.5 MB (spill gone), 641->547 us.
// This round: phase 3 re-partitioned over 64 (ic,par) ITEMS, wave w taking
// items {w, w+12, ...} (5-6 each) instead of 2-3 whole ics. Same weight-load
// count (320 b128/step), rows still read once -- but per-wave work becomes an
// average of 5-6 samples of the liveness distribution, collapsing the
// barrier-C straggler skew that dominated the remaining stall budget.
// Pipeline (5 barriers/step):
//   step top : wave 0 runs PHASE 6 of t-1; waves 1-11 conv1(t)
//   barrier B: conv2 (12 waves, 64-item interleave, per-parity flag gating)
//   barrier C: phase 4 reduce/LIF/list
//   barrier D: phase 5 fc1 gather + XT(t+1) commit (XT aliases RED 8-9)
//   barrier E: next step
__global__ __launch_bounds__(NT, 2) void snn_kernel(
    const float* __restrict__ x,
    const float* __restrict__ bn1_gamma, const float* __restrict__ bn1_beta,
    const float* __restrict__ bn1_mean,  const float* __restrict__ bn1_var,
    const float* __restrict__ bn2_gamma, const float* __restrict__ bn2_beta,
    const float* __restrict__ bn2_mean,  const float* __restrict__ bn2_var,
    const float* __restrict__ beta_c1_raw, const float* __restrict__ beta_c2_raw,
    const float* __restrict__ alpha_raw, const float* __restrict__ rho_raw,
    const float* __restrict__ beta_a_p,  const float* __restrict__ fc_out_w,
    const float* __restrict__ beta_out_p,
    const float* __restrict__ ws, float* __restrict__ out)
{
  extern __shared__ float sm[];
  int* listI = (int*)&sm[L_LIST];
  int* cntI  = (int*)&sm[L_CNT];
  const int tid = threadIdx.x, wave = tid >> 6, lane = tid & 63;
  const int b = blockIdx.x;

  // one-time state zero-init + param/weight staging
  for (int i = tid; i < 6272; i += NT) sm[L_VC1 + i] = 0.f;
  for (int i = tid; i < 1600; i += NT) sm[L_VC2 + i] = 0.f;
  for (int i = tid; i < 2304; i += NT) sm[L_W1 + i] = ws[WS_W1F + i];
  if (tid < 256) {
    sm[L_FCP + tid]       = 1.f / (1.f + expf(-alpha_raw[tid]));
    sm[L_FCP + 256 + tid] = 1.f / (1.f + expf(-rho_raw[tid]));
    sm[L_FCP + 512 + tid] = beta_a_p[tid];
    sm[L_FCS + tid] = 0.f;
    sm[L_FCS + 256 + tid] = 0.f;
    sm[L_FCS + 512 + tid] = 0.f;
  }
  if (tid < 64) {
    float s2 = bn2_gamma[tid] / sqrtf(bn2_var[tid] + 1e-5f);
    sm[L_BN2 + tid]       = s2;
    sm[L_BN2 + 64 + tid]  = bn2_beta[tid] - bn2_mean[tid] * s2;
    sm[L_BN2 + 128 + tid] = 1.f / (1.f + expf(-beta_c2_raw[tid]));
  }

  // conv1 lane mapping: lane = oc*2 + ic
  const int oc1 = lane >> 1, ic1 = lane & 1;
  const float s1v  = bn1_gamma[oc1] / sqrtf(bn1_var[oc1] + 1e-5f);
  const float sh1v = bn1_beta[oc1] - bn1_mean[oc1] * s1v;
  const float b1v  = 1.f / (1.f + expf(-beta_c1_raw[oc1]));
  const float beta_o = 1.f / (1.f + expf(-beta_out_p[0]));

  float v_out = 0.f, o_sum = 0.f;  // wave0, lane<11

  const float* xbase = x + (size_t)b * T_STEPS * 2048;
  const float* w2f  = ws + WS_W2F;
  const float* fc1T = ws + WS_FC1T;
  const float* smw1 = &sm[L_W1];

  // prologue: load+commit x0, prefetch x1 (XT aliases RED 8-9; no RED use yet)
  float4 xpre;
  if (tid < 512) {
    float4 x0 = ((const float4*)xbase)[tid];
    *(float4*)&sm[L_XT + (tid >> 8) * 1040 + ((tid & 255) << 2)] = x0;
    int tn = (T_STEPS > 1) ? 1 : 0;
    xpre = ((const float4*)(xbase + tn * 2048))[tid];
  }

  __syncthreads();

  for (int t = 0; t < T_STEPS; ++t) {
    // ---- phase 2 region: wave 0 phase6(t-1); waves 1-11 conv1(t) ----
    if (wave == 0) {
      if (t > 0) {
        float sk[4];
        #pragma unroll
        for (int k = 0; k < 4; ++k) {
          int j = lane + 64 * k;
          float I = 0.f;
          #pragma unroll
          for (int h2 = 0; h2 < 12; ++h2) I += sm[L_IPART2 + h2 * 256 + j];
          float al = sm[L_FCP + j], rh = sm[L_FCP + 256 + j], ba = sm[L_FCP + 512 + j];
          float vf = sm[L_FCS + j], af = sm[L_FCS + 256 + j], sp0 = sm[L_FCS + 512 + j];
          af = rh * af + (1.f - rh) * sp0;
          float v = al * vf + (1.f - al) * I;
          float sp = (v > 1.f + ba * af) ? 1.f : 0.f;
          sm[L_FCS + j] = v * (1.f - sp);
          sm[L_FCS + 256 + j] = af;
          sm[L_FCS + 512 + j] = sp;
          sk[k] = sp;
        }
        const float4* wop = ((const float4*)(ws + WS_WOUTP)) + lane;
        float p[11];
        #pragma unroll
        for (int o = 0; o < 11; ++o) {
          float4 f = wop[o * 64];          // coalesced, L2-hot
          p[o] = sk[0] * f.x + sk[1] * f.y + sk[2] * f.z + sk[3] * f.w;
        }
        #pragma unroll
        for (int m = 1; m < 64; m <<= 1)
          #pragma unroll
          for (int o = 0; o < 11; ++o) p[o] += __shfl_xor(p[o], m);
        float Isel = p[0];
        #pragma unroll
        for (int o = 1; o < 11; ++o) Isel = (lane == o) ? p[o] : Isel;
        if (lane < 11) {
          v_out = beta_o * v_out + (1.f - beta_o) * Isel;
          o_sum += v_out;
        }
      }
      if (lane == 0) *cntI = 0;
    } else {
      // conv1 rows: waves 1-11 -> rows 0-10; waves 9-11 also rows 11-13.
      // Weights read from LDS [j][64] (lane-consecutive, conflict-free).
      for (int rr = 0; rr < 2; ++rr) {
        int py = (rr == 0) ? (wave - 1) : ((wave >= 9) ? wave + 2 : -1);
        if (py >= 0) {
          float acc[14];
          #pragma unroll
          for (int p = 0; p < 14; ++p) acc[p] = 0.f;
          const float* xr = &sm[L_XT + ic1 * 1040 + py * 64];
          #pragma unroll
          for (int r = 0; r < 6; ++r) {
            float row[32];
            const float4* rp = (const float4*)&xr[r * 32];
            #pragma unroll
            for (int q = 0; q < 8; ++q) {
              float4 f = rp[q];
              row[4*q] = f.x; row[4*q+1] = f.y; row[4*q+2] = f.z; row[4*q+3] = f.w;
            }
            #pragma unroll
            for (int v = 0; v < 6; ++v) {
              float wv = smw1[(r * 6 + v) * 64 + lane];
              #pragma unroll
              for (int px = 0; px < 14; ++px) acc[px] += row[2*px + v] * wv;
            }
          }
          #pragma unroll
          for (int px = 0; px < 14; ++px) acc[px] += __shfl_xor(acc[px], 1);
          if (ic1 == 0) {
            float flag = 0.f;
            #pragma unroll
            for (int px = 0; px < 14; ++px) {
              float c = acc[px] * s1v + sh1v;
              const int vidx = L_VC1 + (py * 14 + px) * 32 + oc1;
              float vold = sm[vidx];
              float v = b1v * vold + (1.f - b1v) * c;
              float s = (v > 1.f) ? 1.f : 0.f;
              sm[vidx] = v * (1.f - s);
              sm[L_SPK1 + oc1 * 228 + py * 16 + px] = s;
              flag += s;
            }
            sm[L_FLAG + oc1 * 14 + py] = flag;
          }
        }
      }
    }
    __syncthreads();                                     // barrier B

    // ---- phase 3: conv2, 64 (ic,par) items round-robin over 12 waves.
    //      Fine-grained interleave averages out liveness variance ->
    //      barrier-C straggler skew collapses. Same load/row-read counts. ----
    {
      float acc[25];
      #pragma unroll
      for (int p = 0; p < 25; ++p) acc[p] = 0.f;
      for (int it = wave; it < 64; it += 12) {
        const int ic  = it >> 1;
        const int par = it & 1;
        const float* fl = &sm[L_FLAG + ic * 14 + par];
        unsigned mm = 0;
        #pragma unroll
        for (int k = 0; k < 7; ++k)
          mm |= (fl[2 * k] != 0.f) ? (1u << k) : 0u;
        if (mm) {
          float w20[20];
          LOADW5(w20, ic, par)
          COMP_PAR(w20, ic, mm, par)
        }
      }
      #pragma unroll
      for (int p = 0; p < 25; ++p) sm[L_RED + wave * 1600 + lane * 25 + p] = acc[p];
    }
    __syncthreads();                                     // barrier C

    // ---- phase 4: reduce 12 buffers + BN + LIF -> spike list ----
    {
      #pragma unroll
      for (int k = 0; k < 3; ++k) {
        int n = tid + NT * k;
        float s = 0.f;
        if (n < 1600) {
          float ssum = 0.f;
          #pragma unroll
          for (int wv = 0; wv < 12; ++wv) ssum += sm[L_RED + wv * 1600 + n];
          int oc = n / 25;
          float c2 = ssum * sm[L_BN2 + oc] + sm[L_BN2 + 64 + oc];
          float b2 = sm[L_BN2 + 128 + oc];
          const int vidx = L_VC2 + n;
          float vold = sm[vidx];
          float v = b2 * vold + (1.f - b2) * c2;
          s = (v > 1.f) ? 1.f : 0.f;
          sm[vidx] = v * (1.f - s);
        }
        unsigned long long mask = __ballot(s > 0.f);
        if (mask) {
          int base = 0;
          if (lane == 0) base = atomicAdd(cntI, __popcll(mask));
          base = __shfl(base, 0);
          if (s > 0.f) {
            int pos = __popcll(mask & ((1ull << lane) - 1ull));
            listI[base + pos] = n;
          }
        }
      }
    }
    __syncthreads();                                     // barrier D

    // ---- phase 5: fc1 sparse gather (12-way, 4 accs) + XT(t+1) commit ----
    {
      if (tid < 512) {
        *(float4*)&sm[L_XT + (tid >> 8) * 1040 + ((tid & 255) << 2)] = xpre;
        int tn = (t + 2 < T_STEPS) ? t + 2 : T_STEPS - 1;
        xpre = ((const float4*)(xbase + tn * 2048))[tid];
      }
      const int nn = *cntI;
      const float4* fc4 = (const float4*)fc1T;
      float4 a0 = {0.f,0.f,0.f,0.f}, a1 = {0.f,0.f,0.f,0.f};
      float4 a2 = {0.f,0.f,0.f,0.f}, a3 = {0.f,0.f,0.f,0.f};
      int i = wave;
      for (; i + 36 < nn; i += 48) {
        int k0 = listI[i], k1 = listI[i + 12], k2 = listI[i + 24], k3 = listI[i + 36];
        float4 f0 = fc4[k0 * 64 + lane];
        float4 f1 = fc4[k1 * 64 + lane];
        float4 f2 = fc4[k2 * 64 + lane];
        float4 f3 = fc4[k3 * 64 + lane];
        a0.x += f0.x; a0.y += f0.y; a0.z += f0.z; a0.w += f0.w;
        a1.x += f1.x; a1.y += f1.y; a1.z += f1.z; a1.w += f1.w;
        a2.x += f2.x; a2.y += f2.y; a2.z += f2.z; a2.w += f2.w;
        a3.x += f3.x; a3.y += f3.y; a3.z += f3.z; a3.w += f3.w;
      }
      for (; i < nn; i += 12) {
        int k = listI[i];
        float4 f = fc4[k * 64 + lane];
        a0.x += f.x; a0.y += f.y; a0.z += f.z; a0.w += f.w;
      }
      a0.x += a1.x + a2.x + a3.x;
      a0.y += a1.y + a2.y + a3.y;
      a0.z += a1.z + a2.z + a3.z;
      a0.w += a1.w + a2.w + a3.w;
      ((float4*)&sm[L_IPART2])[wave * 64 + lane] = a0;   // aliases RED bufs 0-1
    }
    __syncthreads();                                     // barrier E
    // phase 6 for this t runs at the top of the next iteration (wave 0).
  }

  // epilogue: phase 6 for t = T_STEPS-1
  if (wave == 0) {
    float sk[4];
    #pragma unroll
    for (int k = 0; k < 4; ++k) {
      int j = lane + 64 * k;
      float I = 0.f;
      #pragma unroll
      for (int h2 = 0; h2 < 12; ++h2) I += sm[L_IPART2 + h2 * 256 + j];
      float al = sm[L_FCP + j], rh = sm[L_FCP + 256 + j], ba = sm[L_FCP + 512 + j];
      float vf = sm[L_FCS + j], af = sm[L_FCS + 256 + j], sp0 = sm[L_FCS + 512 + j];
      af = rh * af + (1.f - rh) * sp0;
      float v = al * vf + (1.f - al) * I;
      float sp = (v > 1.f + ba * af) ? 1.f : 0.f;
      sk[k] = sp;
    }
    const float4* wop = ((const float4*)(ws + WS_WOUTP)) + lane;
    float p[11];
    #pragma unroll
    for (int o = 0; o < 11; ++o) {
      float4 f = wop[o * 64];
      p[o] = sk[0] * f.x + sk[1] * f.y + sk[2] * f.z + sk[3] * f.w;
    }
    #pragma unroll
    for (int m = 1; m < 64; m <<= 1)
      #pragma unroll
      for (int o = 0; o < 11; ++o) p[o] += __shfl_xor(p[o], m);
    float Isel = p[0];
    #pragma unroll
    for (int o = 1; o < 11; ++o) Isel = (lane == o) ? p[o] : Isel;
    if (lane < 11) {
      v_out = beta_o * v_out + (1.f - beta_o) * Isel;
      o_sum += v_out;
      out[b * 11 + lane] = o_sum * (1.f / T_STEPS);
    }
  }
}

extern "C" void kernel_launch(void* const* d_in, const int* in_sizes, int n_in,
                              void* d_out, int out_size, void* d_ws, size_t ws_size,
                              hipStream_t stream) {
  const float* x            = (const float*)d_in[0];
  const float* conv1_w      = (const float*)d_in[1];
  const float* bn1_gamma    = (const float*)d_in[2];
  const float* bn1_beta     = (const float*)d_in[3];
  const float* bn1_mean     = (const float*)d_in[4];
  const float* bn1_var      = (const float*)d_in[5];
  const float* conv2_w      = (const float*)d_in[6];
  const float* bn2_gamma    = (const float*)d_in[7];
  const float* bn2_beta     = (const float*)d_in[8];
  const float* bn2_mean     = (const float*)d_in[9];
  const float* bn2_var      = (const float*)d_in[10];
  const float* beta_c1_raw  = (const float*)d_in[11];
  const float* beta_c2_raw  = (const float*)d_in[12];
  const float* fc1_w        = (const float*)d_in[13];
  const float* alpha_raw    = (const float*)d_in[14];
  const float* rho_raw      = (const float*)d_in[15];
  const float* beta_a_p     = (const float*)d_in[16];
  const float* fc_out_w     = (const float*)d_in[17];
  const float* beta_out_p   = (const float*)d_in[18];
  float* ws  = (float*)d_ws;
  float* outp = (float*)d_out;

  (void)in_sizes; (void)n_in; (void)out_size; (void)ws_size;

  hipFuncSetAttribute((const void*)snn_kernel,
                      hipFuncAttributeMaxDynamicSharedMemorySize, SMEM_BYTES);

  prep_kernel<<<dim3((WS_TOTAL + 255) / 256), dim3(256), 0, stream>>>(
      conv1_w, conv2_w, fc1_w, fc_out_w, ws);

  snn_kernel<<<dim3(128), dim3(NT), SMEM_BYTES, stream>>>(
      x, bn1_gamma, bn1_beta, bn1_mean, bn1_var,
      bn2_gamma, bn2_beta, bn2_mean, bn2_var,
      beta_c1_raw, beta_c2_raw, alpha_raw, rho_raw, beta_a_p,
      fc_out_w, beta_out_p, ws, outp);
}